// Round 5
// baseline (9957.227 us; speedup 1.0000x reference)
//
#include <hip/hip_runtime.h>
#include <hip/hip_bf16.h>
#include <cstdint>
#include <cstddef>

// S=4096, I=1024, H=1024. 4H=4096. ALL tensors fp32 (per reference).
// out (fp32): all_hidden (4096 x 2048) then final_h (2048), flat.

typedef __attribute__((ext_vector_type(8))) short short8;
typedef __attribute__((ext_vector_type(4))) short short4v;
typedef __attribute__((ext_vector_type(4))) float float4v;
typedef unsigned long long ull;

__device__ __forceinline__ float bf2f(unsigned short u) {
    return __uint_as_float(((unsigned int)u) << 16);
}
__device__ __forceinline__ unsigned short f2bf(float f) {
    __hip_bfloat16 h = __float2bfloat16(f);  // RNE
    return *reinterpret_cast<unsigned short*>(&h);
}
__device__ __forceinline__ float sigm(float x) {
    return 1.f / (1.f + __expf(-x));
}
__device__ __forceinline__ float tanh_fast(float x) {
    return 1.f - 2.f / (__expf(2.f * x) + 1.f);
}

// ---------------------------------------------------------------------------
// Kernel A: x_proj[d][t][j] = b[d][j] + sum_k inp[t][k] * W[d][j][1024+k]
// fp32 -> bf16 LDS tiles -> mfma_f32_16x16x32_bf16 -> fp32 x_proj.
// ---------------------------------------------------------------------------
__global__ __launch_bounds__(256)
void xproj_gemm(const float* __restrict__ inp,
                const float* __restrict__ fw,
                const float* __restrict__ fb,
                const float* __restrict__ bw,
                const float* __restrict__ bb,
                float* __restrict__ xp)
{
    const int d  = blockIdx.z;
    const float* W = d ? bw : fw;
    const float* B = d ? bb : fb;
    const int t0 = blockIdx.y * 128;
    const int n0 = blockIdx.x * 128;

    __shared__ __align__(16) short Ash[128 * 32];
    __shared__ __align__(16) short Bsh[128 * 32];

    const int tid  = threadIdx.x;
    const int lane = tid & 63;
    const int wave = tid >> 6;
    const int wm = (wave & 1) * 64;
    const int wn = (wave >> 1) * 64;
    const int quad = lane >> 4;
    const int l15  = lane & 15;

    float4v acc[4][4];
    float4v zero4 = {0.f, 0.f, 0.f, 0.f};
#pragma unroll
    for (int mi = 0; mi < 4; mi++)
#pragma unroll
        for (int ni = 0; ni < 4; ni++) acc[mi][ni] = zero4;

    for (int k0 = 0; k0 < 1024; k0 += 32) {
#pragma unroll
        for (int s = 0; s < 4; s++) {
            int c   = tid + s * 256;
            int row = c >> 3;
            int ko  = (c & 7) * 4;
            float4v va = *(const float4v*)&inp[(size_t)(t0 + row) * 1024 + k0 + ko];
            float4v vb = *(const float4v*)&W[(size_t)(n0 + row) * 2048 + 1024 + k0 + ko];
            short4v sa, sb;
#pragma unroll
            for (int e = 0; e < 4; e++) {
                sa[e] = (short)f2bf(va[e]);
                sb[e] = (short)f2bf(vb[e]);
            }
            *(short4v*)&Ash[row * 32 + ko] = sa;
            *(short4v*)&Bsh[row * 32 + ko] = sb;
        }
        __syncthreads();

        short8 af[4], bfr[4];
#pragma unroll
        for (int mi = 0; mi < 4; mi++)
            af[mi] = *(const short8*)&Ash[(wm + mi * 16 + l15) * 32 + quad * 8];
#pragma unroll
        for (int ni = 0; ni < 4; ni++)
            bfr[ni] = *(const short8*)&Bsh[(wn + ni * 16 + l15) * 32 + quad * 8];

#pragma unroll
        for (int mi = 0; mi < 4; mi++)
#pragma unroll
            for (int ni = 0; ni < 4; ni++)
                acc[mi][ni] = __builtin_amdgcn_mfma_f32_16x16x32_bf16(
                    af[mi], bfr[ni], acc[mi][ni], 0, 0, 0);
        __syncthreads();
    }

#pragma unroll
    for (int ni = 0; ni < 4; ni++) {
        int gc = n0 + wn + ni * 16 + l15;
        float bias = B[gc];
#pragma unroll
        for (int mi = 0; mi < 4; mi++) {
#pragma unroll
            for (int r = 0; r < 4; r++) {
                int gr = t0 + wm + mi * 16 + quad * 4 + r;
                xp[((size_t)d * 4096 + gr) * 4096 + gc] = acc[mi][ni][r] + bias;
            }
        }
    }
}

// ---------------------------------------------------------------------------
// Kernel B: persistent bidirectional LSTM recurrence.
// 256 blocks (1/CU): dir=bid&1, slot=bid>>1 (128/dir), 8 units/block.
// Thread T: rl=T&31 (z-row), ch=T>>5 (K-slice of 64); w[64] fp32 in VGPRs.
// Tagged-word sync, NREP-replicated: hq[rep][dir][par][1024] ull,
// word = (step_tag<<32)|f32bits(h). Relaxed agent atomics only (no cache
// maintenance). Consumers poll replica slot&(NREP-1) -> hot-line pressure /NREP.
// NO full pre-barrier: wave w polls exactly its own K-slice (words
// [128w,128w+128)), writes its private hsh slice, FMAs immediately.
// One __syncthreads per step (psum, parity-double-buffered).
// ---------------------------------------------------------------------------
template <int FUSED, int NREP>
__global__ __launch_bounds__(512, 2)
void lstm_rec(const float* __restrict__ fw,
              const float* __restrict__ bw,
              const float* __restrict__ fb,
              const float* __restrict__ bb,
              const float* __restrict__ inp,
              const float* __restrict__ xp,
              ull* hq,
              float* __restrict__ out)
{
    const int dir  = blockIdx.x & 1;
    const int slot = blockIdx.x >> 1;          // 0..127
    const int u0   = slot * 8;
    const int rep  = slot & (NREP - 1);
    const int T    = threadIdx.x;              // 0..511
    const int rl   = T & 31;                   // z-row-local
    const int ch   = T >> 5;                   // 0..15, K-slice [64ch,+64)
    const int gate = rl >> 3;
    const int un   = rl & 7;
    const int j    = gate * 1024 + u0 + un;    // global z-row
    const float* W = dir ? bw : fw;

    __shared__ __align__(16) float hsh[1024];
    __shared__ __align__(16) float xsh[1024];      // FUSED only
    __shared__ float psum[2][32 * 17];             // [parity][row][chunk], pad 17

    // Wh weights: cols [ch*64,+64) of row j -> 64 fp32 regs (resident: ~110 VGPR)
    float w[64];
    {
        const float* wr = W + (size_t)j * 2048 + ch * 64;
#pragma unroll
        for (int i = 0; i < 16; i++)
            *(float4v*)&w[4 * i] = *(const float4v*)&wr[4 * i];
    }

    unsigned int w2[32];
    float bj = 0.f;
    if (FUSED) {
        const float* wr2 = W + (size_t)j * 2048 + 1024 + ch * 64;
#pragma unroll
        for (int i = 0; i < 16; i++) {
            float4v v = *(const float4v*)&wr2[4 * i];
            w2[2 * i]     = (unsigned int)f2bf(v[0]) | ((unsigned int)f2bf(v[1]) << 16);
            w2[2 * i + 1] = (unsigned int)f2bf(v[2]) | ((unsigned int)f2bf(v[3]) << 16);
        }
        if (T < 32) bj = (dir ? bb : fb)[j];
    }

    ull* hqd = hq + (size_t)(rep * 2 + dir) * 2048;   // my replica, [par][1024]
    float c = 0.f;   // cell state for unit u0+T (threads T<8)

    for (int t = 0; t < 4096; t++) {
        const int tr  = dir ? (4095 - t) : t;
        const int par = t & 1;

        // independent global loads first (in flight during the poll)
        float xv = 0.f;
        float2 iv;
        if (FUSED) {
            iv = ((const float2*)&inp[(size_t)tr * 1024])[T];
        } else if (T < 32) {
            xv = xp[((size_t)dir * 4096 + tr) * 4096 + j];
        }

        // poll my 2 tagged words (wave-private slice), sleep-backoff retries
        {
            ull* q = &hqd[par * 1024 + 2 * T];
            ull w0 = __hip_atomic_load(q, __ATOMIC_RELAXED, __HIP_MEMORY_SCOPE_AGENT);
            ull w1 = __hip_atomic_load(q + 1, __ATOMIC_RELAXED, __HIP_MEMORY_SCOPE_AGENT);
            while ((unsigned)(w0 >> 32) != (unsigned)t ||
                   (unsigned)(w1 >> 32) != (unsigned)t) {
                __builtin_amdgcn_s_sleep(1);
                w0 = __hip_atomic_load(q, __ATOMIC_RELAXED, __HIP_MEMORY_SCOPE_AGENT);
                w1 = __hip_atomic_load(q + 1, __ATOMIC_RELAXED, __HIP_MEMORY_SCOPE_AGENT);
            }
            hsh[2 * T]     = __uint_as_float((unsigned)w0);
            hsh[2 * T + 1] = __uint_as_float((unsigned)w1);
        }
        if (FUSED) {
            xsh[2 * T]     = iv.x;
            xsh[2 * T + 1] = iv.y;
        }
        // no barrier: hsh/xsh slices are wave-private (wave w wrote [128w,+128))

        // z partial: 64 reg-resident fp32 MACs over my K-slice
        float a0 = 0.f, a1 = 0.f, a2 = 0.f, a3 = 0.f;
        const float4v* h4 = (const float4v*)&hsh[ch * 64];
#pragma unroll
        for (int i = 0; i < 16; i++) {
            float4v hv = h4[i];
            a0 = __builtin_fmaf(w[4 * i + 0], hv.x, a0);
            a1 = __builtin_fmaf(w[4 * i + 1], hv.y, a1);
            a2 = __builtin_fmaf(w[4 * i + 2], hv.z, a2);
            a3 = __builtin_fmaf(w[4 * i + 3], hv.w, a3);
        }
        if (FUSED) {
            const float* xs = &xsh[ch * 64];
#pragma unroll
            for (int i = 0; i < 32; i++) {
                unsigned int dv = w2[i];
                a0 = __builtin_fmaf(bf2f((unsigned short)(dv & 0xffffu)),
                                    xs[2 * i], a0);
                a1 = __builtin_fmaf(bf2f((unsigned short)(dv >> 16)),
                                    xs[2 * i + 1], a1);
            }
        }
        psum[par][rl * 17 + ch] = (a0 + a1) + (a2 + a3);
        __syncthreads();   // the ONLY barrier per step

        // epilogue on wave 0: 32-lane reduce, 1 transcendental/lane, shfl combine
        if (T < 64) {
            float v = 0.f;
            if (T < 32) {
                float s = FUSED ? bj : xv;
                const float* pp = &psum[par][T * 17];
#pragma unroll
                for (int cc = 0; cc < 16; cc++) s += pp[cc];
                v = (T >= 16 && T < 24) ? tanh_fast(s) : sigm(s);   // rows 16-23 = gate g
            }
            float iv2 = __shfl(v, un + 8, 64);
            float gv  = __shfl(v, un + 16, 64);
            float ov  = __shfl(v, un + 24, 64);
            if (T < 8) {
                c = v * c + iv2 * gv;
                float hv = ov * tanh_fast(c);
                out[(size_t)tr * 2048 + dir * 1024 + u0 + T] = hv;
                if (t == 4095)   // final_h: fwd = hs[4095], bwd = hs[0]
                    out[(size_t)4096 * 2048 + dir * 1024 + u0 + T] = hv;
                ull pw = ((ull)(unsigned)(t + 1) << 32) | __float_as_uint(hv);
#pragma unroll
                for (int r2 = 0; r2 < NREP; r2++)
                    __hip_atomic_store(
                        &hq[(size_t)(r2 * 2 + dir) * 2048 + ((t + 1) & 1) * 1024 + u0 + T],
                        pw, __ATOMIC_RELAXED, __HIP_MEMORY_SCOPE_AGENT);
            }
        }
        // next iteration's psum writes go to psum[par^1]; wave 0 can't be lapped
        // past the next __syncthreads, so psum[par] reads above are safe.
    }
}

// ---------------------------------------------------------------------------
extern "C" void kernel_launch(void* const* d_in, const int* in_sizes, int n_in,
                              void* d_out, int out_size, void* d_ws, size_t ws_size,
                              hipStream_t stream)
{
    const float* inp = (const float*)d_in[0];
    const float* fw  = (const float*)d_in[1];
    const float* fb  = (const float*)d_in[2];
    const float* bw  = (const float*)d_in[3];
    const float* bb  = (const float*)d_in[4];

    char* ws = (char*)d_ws;
    ull* hq = (ull*)ws;                              // NREP x 32 KB
    const size_t HQ8  = 8 * 32768;                   // 256 KB
    float* xp = (float*)(ws + HQ8);
    const size_t XP_BYTES = 2ull * 4096 * 4096 * 4;  // 134.2 MB

    float* outp = (float*)d_out;
    if (ws_size >= HQ8 + XP_BYTES) {
        hipMemsetAsync(ws, 0, HQ8, stream);
        dim3 gg(32, 32, 2);
        xproj_gemm<<<gg, 256, 0, stream>>>(inp, fw, fb, bw, bb, xp);
        lstm_rec<0, 8><<<dim3(256), 512, 0, stream>>>(fw, bw, fb, bb, inp, xp,
                                                      hq, outp);
    } else if (ws_size >= HQ8) {
        hipMemsetAsync(ws, 0, HQ8, stream);
        lstm_rec<1, 8><<<dim3(256), 512, 0, stream>>>(fw, bw, fb, bb, inp, nullptr,
                                                      hq, outp);
    } else {
        hipMemsetAsync(ws, 0, 32768, stream);
        lstm_rec<1, 1><<<dim3(256), 512, 0, stream>>>(fw, bw, fb, bb, inp, nullptr,
                                                      hq, outp);
    }
}